// Round 7
// baseline (36.521 us; speedup 1.0000x reference)
//
#include <hip/hip_runtime.h>
#include <math.h>

// Problem constants (B,C,H,W)=(16,1,1024,1024), patch=128
constexpr int B_ = 16;
constexpr int HW = 1024;
constexpr int NPATCH = 1024;       // 16 samples * 8 * 8
constexpr int T1 = 512;

#define GLOAD4(dst, addr) \
    asm volatile("global_load_dwordx4 %0, %1, off" : "=v"(dst) : "v"(addr))

__device__ __forceinline__ unsigned long long pack2(float a, float b) {
    return (unsigned long long)__float_as_uint(a) |
           ((unsigned long long)__float_as_uint(b) << 32);
}

// Fused: one block per 128x128 patch. Records exchanged via device-scope
// atomics (coherence-point RMW, no threadfence/L2-writeback). Last-ticket
// block reduces the 1024 records and writes the scalar.
__global__ __launch_bounds__(T1)
void fused_loss_kernel(const float* __restrict__ labels,
                       const float* __restrict__ preds,
                       unsigned long long* __restrict__ recs,  // 2 u64 per patch
                       unsigned int* __restrict__ counter,
                       float* __restrict__ out)
{
    const int pid = blockIdx.x;
    const int s  = pid >> 6;          // sample
    const int ph = (pid >> 3) & 7;    // patch row
    const int pw = pid & 7;           // patch col
    const size_t base = (size_t)s * (HW * HW) + (size_t)ph * 128 * HW + (size_t)pw * 128;

    const int tid  = threadIdx.x;
    const int col4 = (tid & 31) << 2; // float offset within a 128-float row
    const int row0 = tid >> 5;        // 0..15; 512 threads cover 16 rows per pass

    const float4* px = reinterpret_cast<const float4*>(preds  + base + (size_t)row0 * HW + col4);
    const float4* pt = reinterpret_cast<const float4*>(labels + base + (size_t)row0 * HW + col4);
    constexpr int STRIDE4 = 16 * HW / 4; // float4 stride for 16 rows

    // ---- 16 loads via asm volatile (fixed order, all outstanding) ----
    float4 x0, x1, x2, x3, x4, x5, x6, x7;
    float4 t0, t1, t2, t3, t4, t5, t6, t7;
    GLOAD4(x0, px + 0 * STRIDE4);  GLOAD4(t0, pt + 0 * STRIDE4);
    GLOAD4(x1, px + 1 * STRIDE4);  GLOAD4(t1, pt + 1 * STRIDE4);
    GLOAD4(x2, px + 2 * STRIDE4);  GLOAD4(t2, pt + 2 * STRIDE4);
    GLOAD4(x3, px + 3 * STRIDE4);  GLOAD4(t3, pt + 3 * STRIDE4);
    GLOAD4(x4, px + 4 * STRIDE4);  GLOAD4(t4, pt + 4 * STRIDE4);
    GLOAD4(x5, px + 5 * STRIDE4);  GLOAD4(t5, pt + 5 * STRIDE4);
    GLOAD4(x6, px + 6 * STRIDE4);  GLOAD4(t6, pt + 6 * STRIDE4);
    GLOAD4(x7, px + 7 * STRIDE4);  GLOAD4(t7, pt + 7 * STRIDE4);
    asm volatile("s_waitcnt vmcnt(0)" ::: "memory");
    __builtin_amdgcn_sched_barrier(0);   // rule #18: pin consumers after the wait

    // bce = sum_relu - sum_xt + ln2 * sum_log2(1+e); valid via sum_t (t in {0,1})
    float sum_relu = 0.0f, sum_xt = 0.0f, sum_l2 = 0.0f, sum_t = 0.0f;
    float xmin =  3.0e38f, xmax = -3.0e38f;

    const float NLOG2E = -1.4426950408889634f; // -log2(e)

    const float4 xb[8] = {x0, x1, x2, x3, x4, x5, x6, x7};
    const float4 tb[8] = {t0, t1, t2, t3, t4, t5, t6, t7};
    #pragma unroll
    for (int it = 0; it < 8; ++it) {
        const float xs[4] = {xb[it].x, xb[it].y, xb[it].z, xb[it].w};
        const float ts[4] = {tb[it].x, tb[it].y, tb[it].z, tb[it].w};
        #pragma unroll
        for (int j = 0; j < 4; ++j) {
            const float x = xs[j], t = ts[j];
            const float e = __builtin_amdgcn_exp2f(fabsf(x) * NLOG2E);
            sum_l2   += __builtin_amdgcn_logf(1.0f + e);   // v_log_f32 = log2
            sum_relu += fmaxf(x, 0.0f);
            sum_xt    = fmaf(x, t, sum_xt);
            sum_t    += t;
            xmin = fminf(xmin, x); xmax = fmaxf(xmax, x);
        }
    }
    float bce = sum_relu - sum_xt + 0.6931471805599453f * sum_l2;

    // wave(64) reduction
    #pragma unroll
    for (int o = 32; o > 0; o >>= 1) {
        bce   += __shfl_down(bce, o);
        sum_t += __shfl_down(sum_t, o);
        xmin = fminf(xmin, __shfl_down(xmin, o));
        xmax = fmaxf(xmax, __shfl_down(xmax, o));
    }

    __shared__ float s_a[8], s_b[8], s_c[8], s_d[8];
    __shared__ unsigned int s_ticket;
    const int wave = tid >> 6;
    const int lane = tid & 63;
    if (lane == 0) {
        s_a[wave] = bce; s_b[wave] = xmin; s_c[wave] = xmax; s_d[wave] = sum_t;
    }
    __syncthreads();
    if (tid == 0) {
        float b = 0.0f, xi = 3.0e38f, xa = -3.0e38f, st = 0.0f;
        #pragma unroll
        for (int w = 0; w < T1 / 64; ++w) {
            b += s_a[w];
            xi = fminf(xi, s_b[w]); xa = fmaxf(xa, s_c[w]); st += s_d[w];
        }
        // Device-scope RMW writes: coherent at the coherence point, no fence needed.
        atomicExch(&recs[2 * pid],     pack2(b, xi));
        atomicExch(&recs[2 * pid + 1], pack2(xa, st));
        asm volatile("s_waitcnt vmcnt(0)" ::: "memory"); // records performed before ticket
        s_ticket = atomicAdd(counter, 1u);
    }
    __syncthreads();

    // ---- Last block reduces all patch records ----
    if (s_ticket == NPATCH - 1) {
        float bsum = 0.0f, topo = 0.0f;
        for (int i = tid; i < NPATCH; i += T1) {
            const unsigned long long rA =
                __hip_atomic_load(&recs[2 * i],     __ATOMIC_RELAXED, __HIP_MEMORY_SCOPE_AGENT);
            const unsigned long long rB =
                __hip_atomic_load(&recs[2 * i + 1], __ATOMIC_RELAXED, __HIP_MEMORY_SCOPE_AGENT);
            const float b  = __uint_as_float((unsigned int)rA);
            const float xi = __uint_as_float((unsigned int)(rA >> 32));
            const float xa = __uint_as_float((unsigned int)rB);
            const float st = __uint_as_float((unsigned int)(rB >> 32));
            bsum += b;
            if (st > 0.5f && st < 16383.5f) {   // patch has both 0s and 1s
                // lh = sigmoid(1-x) decreasing in x: pmax=sig(1-xmin), pmin=sig(1-xmax)
                const float pmax = 1.0f / (1.0f + __expf(xi - 1.0f));
                const float pmin = 1.0f / (1.0f + __expf(xa - 1.0f));
                topo += (pmax - 1.0f) * (pmax - 1.0f) + pmin * pmin;
            }
        }
        #pragma unroll
        for (int o = 32; o > 0; o >>= 1) {
            bsum += __shfl_down(bsum, o);
            topo += __shfl_down(topo, o);
        }
        __syncthreads();   // reuse shared arrays
        if (lane == 0) { s_a[wave] = bsum; s_b[wave] = topo; }
        __syncthreads();
        if (tid == 0) {
            float bt = 0.0f, tt = 0.0f;
            #pragma unroll
            for (int w = 0; w < T1 / 64; ++w) { bt += s_a[w]; tt += s_b[w]; }
            out[0] = bt / (float)((size_t)B_ * HW * HW) + tt / (float)B_;
        }
    }
}

extern "C" void kernel_launch(void* const* d_in, const int* in_sizes, int n_in,
                              void* d_out, int out_size, void* d_ws, size_t ws_size,
                              hipStream_t stream) {
    const float* labels = (const float*)d_in[0];
    const float* preds  = (const float*)d_in[1];
    float* out = (float*)d_out;
    unsigned long long* recs = (unsigned long long*)d_ws;          // 1024 * 16 B
    unsigned int* counter = (unsigned int*)((char*)d_ws + NPATCH * 2 * sizeof(unsigned long long));

    hipMemsetAsync(counter, 0, sizeof(unsigned int), stream);      // ticket = 0 each call
    fused_loss_kernel<<<NPATCH, T1, 0, stream>>>(labels, preds, recs, counter, out);
}

// Round 9
// 26.763 us; speedup vs baseline: 1.3646x; 1.3646x over previous
//
#include <hip/hip_runtime.h>
#include <math.h>

// Problem constants (B,C,H,W)=(16,1,1024,1024), patch=128
constexpr int B_ = 16;
constexpr int HW = 1024;
constexpr int NPATCH = 1024;       // 16 samples * 8 * 8
constexpr int T1 = 512;

typedef float floatx4 __attribute__((ext_vector_type(4)));

// Kernel 1: one block per 128x128 patch.
// Per-patch record: {bce_partial_sum, min(pred), max(pred), sum(labels)}
__global__ __launch_bounds__(T1)
void patch_stats_kernel(const float* __restrict__ labels,
                        const float* __restrict__ preds,
                        float4* __restrict__ ws)
{
    const int pid = blockIdx.x;
    const int s  = pid >> 6;          // sample
    const int ph = (pid >> 3) & 7;    // patch row
    const int pw = pid & 7;           // patch col
    const size_t base = (size_t)s * (HW * HW) + (size_t)ph * 128 * HW + (size_t)pw * 128;

    const int tid  = threadIdx.x;
    const int col4 = (tid & 31) << 2; // float offset within a 128-float row
    const int row0 = tid >> 5;        // 0..15; 512 threads cover 16 rows per pass

    const floatx4* px = reinterpret_cast<const floatx4*>(preds  + base + (size_t)row0 * HW + col4);
    const floatx4* pt = reinterpret_cast<const floatx4*>(labels + base + (size_t)row0 * HW + col4);
    constexpr int STRIDE4 = 16 * HW / 4; // float4 stride for 16 rows

    // ---- Deep prefetch with non-temporal loads (streaming: no L2 allocate).
    floatx4 xb[8], tb[8];
    #pragma unroll
    for (int it = 0; it < 8; ++it) {
        xb[it] = __builtin_nontemporal_load(px + it * STRIDE4);
        tb[it] = __builtin_nontemporal_load(pt + it * STRIDE4);
    }
    __builtin_amdgcn_sched_barrier(0);

    // bce = sum_relu - sum_xt + ln2 * sum_log2(1+e); valid via sum_t (t in {0,1})
    float sum_relu = 0.0f, sum_xt = 0.0f, sum_l2 = 0.0f, sum_t = 0.0f;
    float xmin =  3.0e38f, xmax = -3.0e38f;

    const float NLOG2E = -1.4426950408889634f; // -log2(e)

    #pragma unroll
    for (int it = 0; it < 8; ++it) {
        #pragma unroll
        for (int j = 0; j < 4; ++j) {
            const float x = xb[it][j], t = tb[it][j];
            const float e = __builtin_amdgcn_exp2f(fabsf(x) * NLOG2E);
            sum_l2   += __builtin_amdgcn_logf(1.0f + e);   // v_log_f32 = log2
            sum_relu += fmaxf(x, 0.0f);
            sum_xt    = fmaf(x, t, sum_xt);
            sum_t    += t;
            xmin = fminf(xmin, x); xmax = fmaxf(xmax, x);
        }
    }
    float bce = sum_relu - sum_xt + 0.6931471805599453f * sum_l2;

    // wave(64) reduction
    #pragma unroll
    for (int o = 32; o > 0; o >>= 1) {
        bce   += __shfl_down(bce, o);
        sum_t += __shfl_down(sum_t, o);
        xmin = fminf(xmin, __shfl_down(xmin, o));
        xmax = fmaxf(xmax, __shfl_down(xmax, o));
    }

    __shared__ float s_a[8], s_b[8], s_c[8], s_d[8];
    const int wave = tid >> 6;
    const int lane = tid & 63;
    if (lane == 0) {
        s_a[wave] = bce; s_b[wave] = xmin; s_c[wave] = xmax; s_d[wave] = sum_t;
    }
    __syncthreads();
    if (tid == 0) {
        float b = 0.0f, xi = 3.0e38f, xa = -3.0e38f, st = 0.0f;
        #pragma unroll
        for (int w = 0; w < T1 / 64; ++w) {
            b += s_a[w];
            xi = fminf(xi, s_b[w]); xa = fmaxf(xa, s_c[w]); st += s_d[w];
        }
        ws[pid] = make_float4(b, xi, xa, st);
    }
}

// Kernel 2: reduce 1024 patch records to the scalar loss. Overwrites out[0].
__global__ __launch_bounds__(256)
void final_reduce_kernel(const float4* __restrict__ ws, float* __restrict__ out)
{
    const int tid = threadIdx.x;
    float bce = 0.0f, topo = 0.0f;
    #pragma unroll
    for (int k = 0; k < 4; ++k) {
        const float4 rec = ws[tid + 256 * k];
        bce += rec.x;
        // valid: patch contains both 0s and 1s  <=>  0 < sum_t < 16384
        if (rec.w > 0.5f && rec.w < 16383.5f) {
            // lh = sigmoid(1-x) decreasing in x: pmax = sig(1-xmin), pmin = sig(1-xmax)
            const float pmax = 1.0f / (1.0f + __expf(rec.y - 1.0f));
            const float pmin = 1.0f / (1.0f + __expf(rec.z - 1.0f));
            topo += (pmax - 1.0f) * (pmax - 1.0f) + pmin * pmin;
        }
    }
    #pragma unroll
    for (int o = 32; o > 0; o >>= 1) {
        bce  += __shfl_down(bce, o);
        topo += __shfl_down(topo, o);
    }
    __shared__ float s_b[4], s_t[4];
    const int wave = tid >> 6;
    const int lane = tid & 63;
    if (lane == 0) { s_b[wave] = bce; s_t[wave] = topo; }
    __syncthreads();
    if (tid == 0) {
        const float bt = s_b[0] + s_b[1] + s_b[2] + s_b[3];
        const float tt = s_t[0] + s_t[1] + s_t[2] + s_t[3];
        out[0] = bt / (float)((size_t)B_ * HW * HW) + tt / (float)B_;
    }
}

extern "C" void kernel_launch(void* const* d_in, const int* in_sizes, int n_in,
                              void* d_out, int out_size, void* d_ws, size_t ws_size,
                              hipStream_t stream) {
    const float* labels = (const float*)d_in[0];
    const float* preds  = (const float*)d_in[1];
    float*  out = (float*)d_out;
    float4* ws  = (float4*)d_ws;   // 1024 * 16 B = 16 KB

    patch_stats_kernel<<<NPATCH, T1, 0, stream>>>(labels, preds, ws);
    final_reduce_kernel<<<1, 256, 0, stream>>>(ws, out);
}